// Round 15
// baseline (26.879 us; speedup 1.0000x reference)
//
#include <hip/hip_runtime.h>
#include <math.h>

#define BB    16
#define LL    4096
#define TMAX  512
#define DIN   512
#define DHID  256
#define DOUT  3
#define NROW  (BB * TMAX)   // 8192
#define RPB   16            // rows per fused block
#define RPT   8             // rows per thread in phase 1 (row-half split)

typedef __attribute__((ext_vector_type(8))) short bf16x8;   // 8 bf16 = 4 VGPR
typedef __attribute__((ext_vector_type(4))) float f32x4;

static __device__ __forceinline__ ushort f2bf(float x) {
    uint u = __builtin_bit_cast(uint, x);
    u = (u + 0x7FFFu + ((u >> 16) & 1u)) >> 16;
    return (ushort)u;
}

// ---------------------------------------------------------------------------
// ws layout (bytes):
//   [0 .. 256K)   pack: fragment-major W1 bf16, 256KB
//     pack[((nb*16 + ktc)*64 + g*16 + m)*8 + j] = W1[k][col],
//       col = nb*16+m, k = ktc*32 + g*8 + j
//     -> a wave's B-fragment load (64 lanes x 16B) is 1KB CONTIGUOUS.
// ---------------------------------------------------------------------------

// Pack-only prep (scan moved into fused blocks).
__global__ __launch_bounds__(512) void pack_kernel(const float* __restrict__ W1,
                                                   ushort* __restrict__ pack) {
    __shared__ float t[64][65];
    const int tb = blockIdx.x;            // 0..31: 8 k-tiles x 4 n-tiles
    const int k0 = (tb >> 2) * 64;
    const int n0 = (tb & 3) * 64;
    const int tid = threadIdx.x;
    const int r  = tid >> 3;              // 0..63
    const int c8 = (tid & 7) * 8;         // 0..56
    #pragma unroll
    for (int i = 0; i < 2; ++i) {
        const float4 v =
            *(const float4*)&W1[(size_t)(k0 + r) * DHID + n0 + c8 + i * 4];
        t[r][c8 + i * 4 + 0] = v.x;
        t[r][c8 + i * 4 + 1] = v.y;
        t[r][c8 + i * 4 + 2] = v.z;
        t[r][c8 + i * 4 + 3] = v.w;
    }
    __syncthreads();
    const int col = n0 + r;
    const int kk  = k0 + c8;
    const int nb  = col >> 4;
    const int mm  = col & 15;
    const int ktc = kk >> 5;
    const int gg  = (kk >> 3) & 3;
    ushort tmp[8];
    #pragma unroll
    for (int j = 0; j < 8; ++j) tmp[j] = f2bf(t[c8 + j][r]);
    *(uint4*)&pack[(size_t)(((nb * 16 + ktc) * 64) + gg * 16 + mm) * 8] =
        *(const uint4*)tmp;
}

// ---------------------------------------------------------------------------
// Fused: in-block duration scan + segment-mean (16 rows -> swizzled LDS
// A-tile) + MFMA GEMM (16x256, K=512) + fused layer-2 -> d_out.
// 256 thr / 4 waves; 512 blocks (XCD-chunked).
// Phase 0: per-block shfl_up scan of this batch's 512 d_eff values
//          (6 shfl steps/wave + 4-wave LDS combine, 2 barriers); the 16
//          rows' (start,len) published via LDS table.
// Phase 1: thread = (col-quad ct = tid&127, row-half rh = tid>>7);
//          8 rows x nmax clamped UNCONDITIONAL float4 loads + cndmask adds.
//          LDS write ushort4 at byte (ct*8)^((rl&7)<<4).
// Phase 2: wave w (0..3) owns cols w*64..w*64+63 (4 frags, 4 MFMA chains);
//          B-loads contiguous 1KB/wave from fragment-major pack.
//   A-frag: lane holds A[row=l&15][k=8*(l>>4)+j] via swizzled 16B LDS read
//   C/D:    col = l&15, row = (l>>4)*4 + reg
// ---------------------------------------------------------------------------
__global__ __launch_bounds__(256, 2) void fused_kernel(
    const float* __restrict__ hs, const int* __restrict__ ds,
    const int* __restrict__ lmax, const ushort* __restrict__ pack,
    const float* __restrict__ b1, const float* __restrict__ W2,
    const float* __restrict__ b2, float* __restrict__ out) {
    __shared__ ushort Asw[RPB * DIN];        // 16KB, XOR-swizzled rows
    __shared__ float  red[4][RPB][DOUT];     // 768B
    __shared__ int    wsum[4];
    __shared__ int    stab[RPB], ltab[RPB];

    const int raw  = blockIdx.x;             // 0..511
    const int bid  = (raw & 7) * 64 + (raw >> 3);   // XCD-chunked bijection
    const int row0 = bid * RPB;
    const int b    = row0 >> 9;              // batch (512 rows per batch)
    const int t0   = row0 & (TMAX - 1);      // row0 within batch
    const int tid  = threadIdx.x;
    const int w    = tid >> 6;               // wave 0..3
    const int l    = tid & 63;
    const int m    = l & 15;
    const int g    = l >> 4;
    const int ct   = tid & 127;              // col-quad owner (phase 1)
    const int rh   = tid >> 7;               // row-half (phase 1)

    // ---- phase 0: in-block duration scan (this batch, 512 elems) ----
    {
        const float mult = (float)LL / (float)lmax[0];
        const int2 dv = *(const int2*)&ds[b * TMAX + tid * 2];
        int d0 = max((int)floorf((float)dv.x * mult), 1);
        int d1 = max((int)floorf((float)dv.y * mult), 1);
        const int deff0 = (dv.x > 0) ? d0 : 0;
        const int deff1 = (dv.y > 0) ? d1 : 0;
        int ps = deff0 + deff1;              // pair sum
        // wave-inclusive scan over pair sums
        #pragma unroll
        for (int off = 1; off < 64; off <<= 1) {
            const int tmp = __shfl_up(ps, off, 64);
            if (l >= off) ps += tmp;
        }
        if (l == 63) wsum[w] = ps;
        __syncthreads();
        int woff = 0;
        #pragma unroll
        for (int ww = 0; ww < 4; ++ww) woff += (ww < w) ? wsum[ww] : 0;
        const int incl  = woff + ps;                 // inclusive over pairs
        const int s1    = incl - deff1;              // start of elem e1
        const int s0    = s1 - deff0;                // start of elem e0
        const int e0    = tid * 2;
        if (e0 >= t0 && e0 < t0 + RPB)     { stab[e0 - t0] = s0; ltab[e0 - t0] = deff0; }
        if (e0 + 1 >= t0 && e0 + 1 < t0 + RPB) { stab[e0 + 1 - t0] = s1; ltab[e0 + 1 - t0] = deff1; }
    }
    __syncthreads();

    // ---- phase 1: segment means, 8 rows/thread, float4 clamped loads ----
    int s_arr[RPT], n_arr[RPT], last_arr[RPT];
    int nmax = 0;
    #pragma unroll
    for (int rr = 0; rr < RPT; ++rr) {
        const int rl  = rh * RPT + rr;
        const int len = ltab[rl];
        int s = stab[rl];
        int e = min(s + len, LL);
        s = min(s, LL);
        const int n = e - s;
        s_arr[rr]    = s;
        n_arr[rr]    = n;
        last_arr[rr] = min(max(e - 1, 0), LL - 1);   // always-valid frame
        nmax = max(nmax, n);
    }
    float4 a[RPT];
    #pragma unroll
    for (int rr = 0; rr < RPT; ++rr) a[rr] = make_float4(0.f, 0.f, 0.f, 0.f);

    const float* base = hs + (size_t)b * LL * DIN + ct * 4;
    for (int i = 0; i < nmax; ++i) {
        float4 v[RPT];
        #pragma unroll
        for (int rr = 0; rr < RPT; ++rr) {
            const int idx = min(s_arr[rr] + i, last_arr[rr]);
            v[rr] = *(const float4*)(base + (size_t)idx * DIN);
        }
        #pragma unroll
        for (int rr = 0; rr < RPT; ++rr) {
            const bool ok = (i < n_arr[rr]);
            a[rr].x += ok ? v[rr].x : 0.0f;
            a[rr].y += ok ? v[rr].y : 0.0f;
            a[rr].z += ok ? v[rr].z : 0.0f;
            a[rr].w += ok ? v[rr].w : 0.0f;
        }
    }
    #pragma unroll
    for (int rr = 0; rr < RPT; ++rr) {
        const int rl = rh * RPT + rr;
        const float inv = (n_arr[rr] > 0) ? 1.0f / (float)n_arr[rr] : 0.0f;
        ushort4 u;
        u.x = f2bf(a[rr].x * inv);
        u.y = f2bf(a[rr].y * inv);
        u.z = f2bf(a[rr].z * inv);
        u.w = f2bf(a[rr].w * inv);
        *(ushort4*)((char*)Asw + rl * 1024 + ((ct * 8) ^ ((rl & 7) << 4))) = u;
    }
    __syncthreads();

    // ---- phase 2: GEMM 16 x 64 (this wave) over K = 512, 4 acc chains ----
    f32x4 acc[4] = {{0.f, 0.f, 0.f, 0.f}, {0.f, 0.f, 0.f, 0.f},
                    {0.f, 0.f, 0.f, 0.f}, {0.f, 0.f, 0.f, 0.f}};

    const ushort* bb   = pack + (size_t)l * 8;
    const char* abase  = (const char*)Asw + m * 1024;
    const int   aswz   = (m & 7) << 4;

    #pragma unroll 4
    for (int ktc = 0; ktc < 16; ++ktc) {
        const int aoff = (g * 16 + ktc * 64) ^ aswz;
        const bf16x8 av = *(const bf16x8*)(abase + aoff);
        #pragma unroll
        for (int fc = 0; fc < 4; ++fc) {
            const bf16x8 bv =
                *(const bf16x8*)(bb + (size_t)(((w * 4 + fc) * 16 + ktc) * 512));
            acc[fc] = __builtin_amdgcn_mfma_f32_16x16x32_bf16(av, bv, acc[fc],
                                                              0, 0, 0);
        }
    }

    // ---- phase 3: layer 2 (h = relu(acc+b1); p += h*W2), reduce, store ----
    float p[4][3];
    #pragma unroll
    for (int r = 0; r < 4; ++r)
        #pragma unroll
        for (int o = 0; o < 3; ++o) p[r][o] = 0.0f;

    #pragma unroll
    for (int fc = 0; fc < 4; ++fc) {
        const int col = w * 64 + fc * 16 + m;
        const float bb1 = b1[col];
        const float w20 = W2[col * 3 + 0];
        const float w21 = W2[col * 3 + 1];
        const float w22 = W2[col * 3 + 2];
        #pragma unroll
        for (int r = 0; r < 4; ++r) {
            const float h = fmaxf(acc[fc][r] + bb1, 0.0f);
            p[r][0] = fmaf(h, w20, p[r][0]);
            p[r][1] = fmaf(h, w21, p[r][1]);
            p[r][2] = fmaf(h, w22, p[r][2]);
        }
    }
    #pragma unroll
    for (int mask = 1; mask < 16; mask <<= 1)
        #pragma unroll
        for (int r = 0; r < 4; ++r)
            #pragma unroll
            for (int o = 0; o < 3; ++o)
                p[r][o] += __shfl_xor(p[r][o], mask, 64);

    if (m == 0) {
        #pragma unroll
        for (int r = 0; r < 4; ++r)
            #pragma unroll
            for (int o = 0; o < 3; ++o)
                red[w][g * 4 + r][o] = p[r][o];
    }
    __syncthreads();

    if (tid < RPB * DOUT) {
        const int rl = tid / 3;
        const int o  = tid % 3;
        const float v = red[0][rl][o] + red[1][rl][o] + red[2][rl][o] +
                        red[3][rl][o] + b2[o];
        out[(size_t)(row0 + rl) * DOUT + o] = fmaxf(v, 0.0f);
    }
}

extern "C" void kernel_launch(void* const* d_in, const int* in_sizes, int n_in,
                              void* d_out, int out_size, void* d_ws, size_t ws_size,
                              hipStream_t stream) {
    const float* hs  = (const float*)d_in[0];
    const int*   ds  = (const int*)d_in[1];
    const float* W1  = (const float*)d_in[2];
    const float* b1  = (const float*)d_in[3];
    const float* W2  = (const float*)d_in[4];
    const float* b2  = (const float*)d_in[5];
    const int*   lmx = (const int*)d_in[6];

    ushort* pack = (ushort*)d_ws;

    pack_kernel<<<32, 512, 0, stream>>>(W1, pack);
    fused_kernel<<<NROW / RPB, 256, 0, stream>>>(hs, ds, lmx, pack, b1, W2,
                                                 b2, (float*)d_out);
}

// Round 16
// 25.831 us; speedup vs baseline: 1.0406x; 1.0406x over previous
//
#include <hip/hip_runtime.h>
#include <math.h>

#define BB    16
#define LL    4096
#define TMAX  512
#define DIN   512
#define DHID  256
#define DOUT  3
#define NROW  (BB * TMAX)   // 8192
#define RPB   16            // rows per fused block
#define RPT   8             // rows per thread in phase 1 (row-half split)

typedef __attribute__((ext_vector_type(8))) short bf16x8;   // 8 bf16 = 4 VGPR
typedef __attribute__((ext_vector_type(4))) float f32x4;

static __device__ __forceinline__ ushort f2bf(float x) {
    uint u = __builtin_bit_cast(uint, x);
    u = (u + 0x7FFFu + ((u >> 16) & 1u)) >> 16;
    return (ushort)u;
}

// ---------------------------------------------------------------------------
// ws layout (bytes):
//   [0    .. 32K )   starts (int[8192])
//   [32K  .. 64K )   lens   (int[8192])
//   [64K  .. 320K)   pack: fragment-major W1 bf16, 256KB
//     pack[((nb*16 + ktc)*64 + g*16 + m)*8 + j] = W1[k][col],
//       col = nb*16+m, k = ktc*32 + g*8 + j
//     -> a wave's B-fragment load (64 lanes x 16B) is 1KB CONTIGUOUS.
// ---------------------------------------------------------------------------

__global__ __launch_bounds__(512) void prep_kernel(
    const int* __restrict__ ds, const int* __restrict__ lmax,
    const float* __restrict__ W1, int* __restrict__ starts,
    int* __restrict__ lens, ushort* __restrict__ pack) {
    __shared__ int   sbuf[TMAX];
    __shared__ float t[64][65];
    const int bid = blockIdx.x;
    const int tid = threadIdx.x;

    if (bid < BB) {                       // ---- scan ----
        const int b = bid;
        const float mult = (float)LL / (float)lmax[0];
        const int dsv = ds[b * TMAX + tid];
        int d = (int)floorf((float)dsv * mult);
        d = max(d, 1);
        const int deff = (dsv > 0) ? d : 0;
        sbuf[tid] = deff;
        __syncthreads();
        for (int off = 1; off < TMAX; off <<= 1) {
            int x = (tid >= off) ? sbuf[tid - off] : 0;
            __syncthreads();
            sbuf[tid] += x;
            __syncthreads();
        }
        starts[b * TMAX + tid] = sbuf[tid] - deff;
        lens[b * TMAX + tid]   = deff;
    } else {                              // ---- W1 -> fragment-major pack ----
        const int tb = bid - BB;          // 0..31: 8 k-tiles x 4 n-tiles
        const int k0 = (tb >> 2) * 64;
        const int n0 = (tb & 3) * 64;
        const int r  = tid >> 3;          // 0..63
        const int c8 = (tid & 7) * 8;     // 0..56
        #pragma unroll
        for (int i = 0; i < 2; ++i) {
            const float4 v =
                *(const float4*)&W1[(size_t)(k0 + r) * DHID + n0 + c8 + i * 4];
            t[r][c8 + i * 4 + 0] = v.x;
            t[r][c8 + i * 4 + 1] = v.y;
            t[r][c8 + i * 4 + 2] = v.z;
            t[r][c8 + i * 4 + 3] = v.w;
        }
        __syncthreads();
        const int col = n0 + r;
        const int kk  = k0 + c8;
        const int nb  = col >> 4;
        const int mm  = col & 15;
        const int ktc = kk >> 5;
        const int gg  = (kk >> 3) & 3;
        ushort tmp[8];
        #pragma unroll
        for (int j = 0; j < 8; ++j) tmp[j] = f2bf(t[c8 + j][r]);
        *(uint4*)&pack[(size_t)(((nb * 16 + ktc) * 64) + gg * 16 + mm) * 8] =
            *(const uint4*)tmp;
    }
}

// ---------------------------------------------------------------------------
// Fused: segment-mean (16 rows -> swizzled LDS A-tile) + MFMA GEMM
// (16x256, K=512) + fused layer-2 -> d_out.
// 256 thr / 4 waves; 512 blocks (XCD-chunked).
// Phase 1: thread = (col-quad ct = tid&127, row-half rh = tid>>7);
//          8 rows x nmax clamped UNCONDITIONAL float4 loads + cndmask adds.
//          LDS write ushort4 at byte (ct*8)^((rl&7)<<4).
// Phase 2: wave w (0..3) owns cols w*64..w*64+63 (4 frags, 4 MFMA chains).
//          B pipeline: FULL unroll over 16 ktc, prefetch distance 4
//          (bpre[16], static indices) -> ~13-16 loads in flight vs ~5
//          compiler-scheduled (R13 ablation: phase 2 latency-bound 6.4us
//          vs ~2us BW floor).
//   A-frag: lane holds A[row=l&15][k=8*(l>>4)+j] via swizzled 16B LDS read
//   C/D:    col = l&15, row = (l>>4)*4 + reg
// ---------------------------------------------------------------------------
__global__ __launch_bounds__(256, 2) void fused_kernel(
    const float* __restrict__ hs, const int* __restrict__ starts,
    const int* __restrict__ lens, const ushort* __restrict__ pack,
    const float* __restrict__ b1, const float* __restrict__ W2,
    const float* __restrict__ b2, float* __restrict__ out) {
    __shared__ ushort Asw[RPB * DIN];        // 16KB, XOR-swizzled rows
    __shared__ float  red[4][RPB][DOUT];     // 768B

    const int raw  = blockIdx.x;             // 0..511
    const int bid  = (raw & 7) * 64 + (raw >> 3);   // XCD-chunked bijection
    const int row0 = bid * RPB;
    const int b    = row0 >> 9;              // batch (512 rows per batch)
    const int tid  = threadIdx.x;
    const int w    = tid >> 6;               // wave 0..3
    const int l    = tid & 63;
    const int m    = l & 15;
    const int g    = l >> 4;
    const int ct   = tid & 127;              // col-quad owner (phase 1)
    const int rh   = tid >> 7;               // row-half (phase 1)

    // ---- phase 1: segment means, 8 rows/thread, float4 clamped loads ----
    int s_arr[RPT], n_arr[RPT], last_arr[RPT];
    int nmax = 0;
    #pragma unroll
    for (int rr = 0; rr < RPT; ++rr) {
        const int row = row0 + rh * RPT + rr;
        const int len = lens[row];
        int s = starts[row];
        int e = min(s + len, LL);
        s = min(s, LL);
        const int n = e - s;
        s_arr[rr]    = s;
        n_arr[rr]    = n;
        last_arr[rr] = min(max(e - 1, 0), LL - 1);   // always-valid frame
        nmax = max(nmax, n);
    }
    float4 a[RPT];
    #pragma unroll
    for (int rr = 0; rr < RPT; ++rr) a[rr] = make_float4(0.f, 0.f, 0.f, 0.f);

    const float* base = hs + (size_t)b * LL * DIN + ct * 4;
    for (int i = 0; i < nmax; ++i) {
        float4 v[RPT];
        #pragma unroll
        for (int rr = 0; rr < RPT; ++rr) {
            const int idx = min(s_arr[rr] + i, last_arr[rr]);
            v[rr] = *(const float4*)(base + (size_t)idx * DIN);
        }
        #pragma unroll
        for (int rr = 0; rr < RPT; ++rr) {
            const bool ok = (i < n_arr[rr]);
            a[rr].x += ok ? v[rr].x : 0.0f;
            a[rr].y += ok ? v[rr].y : 0.0f;
            a[rr].z += ok ? v[rr].z : 0.0f;
            a[rr].w += ok ? v[rr].w : 0.0f;
        }
    }
    #pragma unroll
    for (int rr = 0; rr < RPT; ++rr) {
        const int rl = rh * RPT + rr;
        const float inv = (n_arr[rr] > 0) ? 1.0f / (float)n_arr[rr] : 0.0f;
        ushort4 u;
        u.x = f2bf(a[rr].x * inv);
        u.y = f2bf(a[rr].y * inv);
        u.z = f2bf(a[rr].z * inv);
        u.w = f2bf(a[rr].w * inv);
        *(ushort4*)((char*)Asw + rl * 1024 + ((ct * 8) ^ ((rl & 7) << 4))) = u;
    }
    __syncthreads();

    // ---- phase 2: GEMM 16 x 64 (this wave), K = 512, deep B pipeline ----
    f32x4 acc[4] = {{0.f, 0.f, 0.f, 0.f}, {0.f, 0.f, 0.f, 0.f},
                    {0.f, 0.f, 0.f, 0.f}, {0.f, 0.f, 0.f, 0.f}};

    const ushort* bb   = pack + (size_t)l * 8;
    const char* abase  = (const char*)Asw + m * 1024;
    const int   aswz   = (m & 7) << 4;

    // bpre[(ktc & 3)*4 + fc] holds B for ktc; prefetch distance 4.
    bf16x8 bpre[16];
    #pragma unroll
    for (int q = 0; q < 4; ++q)
        #pragma unroll
        for (int fc = 0; fc < 4; ++fc)
            bpre[q * 4 + fc] =
                *(const bf16x8*)(bb + (size_t)(((w * 4 + fc) * 16 + q) * 512));

    #pragma unroll
    for (int ktc = 0; ktc < 16; ++ktc) {
        const int slot = (ktc & 3) * 4;
        const int aoff = (g * 16 + ktc * 64) ^ aswz;
        const bf16x8 av = *(const bf16x8*)(abase + aoff);
        #pragma unroll
        for (int fc = 0; fc < 4; ++fc)
            acc[fc] = __builtin_amdgcn_mfma_f32_16x16x32_bf16(
                av, bpre[slot + fc], acc[fc], 0, 0, 0);
        if (ktc < 12) {
            #pragma unroll
            for (int fc = 0; fc < 4; ++fc)
                bpre[slot + fc] = *(const bf16x8*)(
                    bb + (size_t)(((w * 4 + fc) * 16 + (ktc + 4)) * 512));
        }
    }

    // ---- phase 3: layer 2 (h = relu(acc+b1); p += h*W2), reduce, store ----
    float p[4][3];
    #pragma unroll
    for (int r = 0; r < 4; ++r)
        #pragma unroll
        for (int o = 0; o < 3; ++o) p[r][o] = 0.0f;

    #pragma unroll
    for (int fc = 0; fc < 4; ++fc) {
        const int col = w * 64 + fc * 16 + m;
        const float bb1 = b1[col];
        const float w20 = W2[col * 3 + 0];
        const float w21 = W2[col * 3 + 1];
        const float w22 = W2[col * 3 + 2];
        #pragma unroll
        for (int r = 0; r < 4; ++r) {
            const float h = fmaxf(acc[fc][r] + bb1, 0.0f);
            p[r][0] = fmaf(h, w20, p[r][0]);
            p[r][1] = fmaf(h, w21, p[r][1]);
            p[r][2] = fmaf(h, w22, p[r][2]);
        }
    }
    #pragma unroll
    for (int mask = 1; mask < 16; mask <<= 1)
        #pragma unroll
        for (int r = 0; r < 4; ++r)
            #pragma unroll
            for (int o = 0; o < 3; ++o)
                p[r][o] += __shfl_xor(p[r][o], mask, 64);

    if (m == 0) {
        #pragma unroll
        for (int r = 0; r < 4; ++r)
            #pragma unroll
            for (int o = 0; o < 3; ++o)
                red[w][g * 4 + r][o] = p[r][o];
    }
    __syncthreads();

    if (tid < RPB * DOUT) {
        const int rl = tid / 3;
        const int o  = tid % 3;
        const float v = red[0][rl][o] + red[1][rl][o] + red[2][rl][o] +
                        red[3][rl][o] + b2[o];
        out[(size_t)(row0 + rl) * DOUT + o] = fmaxf(v, 0.0f);
    }
}

extern "C" void kernel_launch(void* const* d_in, const int* in_sizes, int n_in,
                              void* d_out, int out_size, void* d_ws, size_t ws_size,
                              hipStream_t stream) {
    const float* hs  = (const float*)d_in[0];
    const int*   ds  = (const int*)d_in[1];
    const float* W1  = (const float*)d_in[2];
    const float* b1  = (const float*)d_in[3];
    const float* W2  = (const float*)d_in[4];
    const float* b2  = (const float*)d_in[5];
    const int*   lmx = (const int*)d_in[6];

    char*   wsb    = (char*)d_ws;
    int*    starts = (int*)wsb;
    int*    lens   = (int*)(wsb + 32 * 1024);
    ushort* pack   = (ushort*)(wsb + 64 * 1024);

    prep_kernel<<<BB + 32, 512, 0, stream>>>(ds, lmx, W1, starts, lens, pack);
    fused_kernel<<<NROW / RPB, 256, 0, stream>>>(hs, starts, lens, pack, b1, W2,
                                                 b2, (float*)d_out);
}